// Round 1
// baseline (803.312 us; speedup 1.0000x reference)
//
#include <hip/hip_runtime.h>
#include <cmath>

#define DIM 192
#define V (DIM * DIM * DIM)

struct KW13 { float w[13]; };

// ---------------- separable 1D convolution pass (zero padding) -------------
template <int KS, int STRIDE>
__global__ void conv_pass(const float* __restrict__ in, float* __restrict__ out,
                          KW13 kw) {
    int i = blockIdx.x * blockDim.x + threadIdx.x;
    if (i >= V) return;
    int c = (i / STRIDE) % DIM;            // coordinate along conv axis
    constexpr int H = KS / 2;
    float s = 0.f;
#pragma unroll
    for (int t = 0; t < KS; ++t) {
        int cc = c + (t - H);
        if (cc >= 0 && cc < DIM) s += kw.w[t] * in[i + (t - H) * STRIDE];
    }
    out[i] = s;
}

// ---------------- elementwise a - b -> dst ---------------------------------
__global__ void sub_kernel(const float* __restrict__ a, const float* __restrict__ b,
                           float* __restrict__ dst) {
    int i = blockIdx.x * blockDim.x + threadIdx.x;
    if (i >= V) return;
    dst[i] = a[i] - b[i];
}

// ---------------- derivatives of smooth (G sigma=1.0) ----------------------
__global__ void deriv_kernel(const float* __restrict__ g,
                             float* __restrict__ ch3, float* __restrict__ ch4,
                             float* __restrict__ ch5) {
    int i = blockIdx.x * blockDim.x + threadIdx.x;
    if (i >= V) return;
    int x = i % DIM;
    int y = (i / DIM) % DIM;
    int z = i / (DIM * DIM);
    float c  = g[i];
    float xm = (x > 0)       ? g[i - 1]         : 0.f;
    float xp = (x < DIM - 1) ? g[i + 1]         : 0.f;
    float ym = (y > 0)       ? g[i - DIM]       : 0.f;
    float yp = (y < DIM - 1) ? g[i + DIM]       : 0.f;
    float zm = (z > 0)       ? g[i - DIM * DIM] : 0.f;
    float zp = (z < DIM - 1) ? g[i + DIM * DIM] : 0.f;
    float gx = 0.5f * (xp - xm);
    float gy = 0.5f * (yp - ym);
    float gz = 0.5f * (zp - zm);
    float hxx = xm - 2.f * c + xp;
    float hyy = ym - 2.f * c + yp;
    float hzz = zm - 2.f * c + zp;
    ch3[i] = hxx + hyy + hzz;
    ch4[i] = sqrtf(gx * gx + gy * gy + gz * gz + 1e-8f);
    float r = fabsf(gy) / (fabsf(gx) + 1e-3f);
    ch5[i] = fminf(fmaxf(r, 0.f), 20.f);
}

// ---------------- finalize: move ch3 temp (o0) -> o3, write ch0 = raw ------
__global__ void finalize_kernel(const float* __restrict__ raw,
                                float* __restrict__ o0, float* __restrict__ o3) {
    int i = blockIdx.x * blockDim.x + threadIdx.x;
    if (i >= V) return;
    float t = o0[i];
    o3[i] = t;
    o0[i] = raw[i];
}

// ---------------- per-channel sum / sumsq reduction ------------------------
__global__ void reduce_kernel(const float* __restrict__ feat,
                              double* __restrict__ sums) {
    int c = blockIdx.y;
    const float* p = feat + (size_t)c * V;
    double s = 0.0, s2 = 0.0;
    for (int i = blockIdx.x * blockDim.x + threadIdx.x; i < V;
         i += gridDim.x * blockDim.x) {
        double v = (double)p[i];
        s += v;
        s2 += v * v;
    }
    __shared__ double sh[256], sh2[256];
    int t = threadIdx.x;
    sh[t] = s; sh2[t] = s2;
    __syncthreads();
    for (int o = 128; o > 0; o >>= 1) {
        if (t < o) { sh[t] += sh[t + o]; sh2[t] += sh2[t + o]; }
        __syncthreads();
    }
    if (t == 0) {
        atomicAdd(&sums[2 * c],     sh[0]);
        atomicAdd(&sums[2 * c + 1], sh2[0]);
    }
}

// ---------------- normalize in place ---------------------------------------
__global__ void normalize_kernel(float* __restrict__ out,
                                 const double* __restrict__ sums) {
    int i = blockIdx.x * blockDim.x + threadIdx.x;
    if (i >= 6 * V) return;
    int c = i / V;
    double s  = sums[2 * c];
    double s2 = sums[2 * c + 1];
    double mean = s / (double)V;
    double var  = (s2 - s * s / (double)V) / (double)(V - 1);
    float stdv  = (float)sqrt(var);
    out[i] = ((float)((double)out[i] - mean)) / (stdv + 1e-8f);
}

// ---------------- host-side Gaussian weights -------------------------------
static void gauss_w(double sigma, KW13* kw, int* ks_out) {
    int ks = (int)(4.0 * sigma + 1.0);
    if (ks % 2 == 0) ks++;
    double sum = 0.0;
    double tmp[13];
    for (int i = 0; i < ks; ++i) {
        double x = (double)(i - ks / 2);
        tmp[i] = exp(-0.5 * x * x / (sigma * sigma));
        sum += tmp[i];
    }
    for (int i = 0; i < 13; ++i) kw->w[i] = (i < ks) ? (float)(tmp[i] / sum) : 0.f;
    *ks_out = ks;
}

extern "C" void kernel_launch(void* const* d_in, const int* in_sizes, int n_in,
                              void* d_out, int out_size, void* d_ws, size_t ws_size,
                              hipStream_t stream) {
    const float* raw = (const float*)d_in[0];
    float* out = (float*)d_out;
    float* o[6];
    for (int c = 0; c < 6; ++c) o[c] = out + (size_t)c * V;
    double* sums = (double*)d_ws;

    hipMemsetAsync(d_ws, 0, 12 * sizeof(double), stream);

    KW13 k10, k15, k20, k30;
    int ks;
    gauss_w(1.0, &k10, &ks);   // ks = 5
    gauss_w(1.5, &k15, &ks);   // ks = 7
    gauss_w(2.0, &k20, &ks);   // ks = 9
    gauss_w(3.0, &k30, &ks);   // ks = 13

    dim3 blk(256);
    dim3 grd(V / 256);         // 192^3 divisible by 256

    constexpr int SZ = DIM * DIM;  // z-stride
    constexpr int SY = DIM;        // y-stride

    // G(1.0) -> o3
    conv_pass<5, SZ><<<grd, blk, 0, stream>>>(raw,  o[1], k10);
    conv_pass<5, SY><<<grd, blk, 0, stream>>>(o[1], o[2], k10);
    conv_pass<5, 1 ><<<grd, blk, 0, stream>>>(o[2], o[3], k10);
    // G(1.5) -> o4
    conv_pass<7, SZ><<<grd, blk, 0, stream>>>(raw,  o[1], k15);
    conv_pass<7, SY><<<grd, blk, 0, stream>>>(o[1], o[2], k15);
    conv_pass<7, 1 ><<<grd, blk, 0, stream>>>(o[2], o[4], k15);
    // ch1 = G10 - G15 -> o1
    sub_kernel<<<grd, blk, 0, stream>>>(o[3], o[4], o[1]);
    // G(2.0) -> o5
    conv_pass<9, SZ><<<grd, blk, 0, stream>>>(raw,  o[2], k20);
    conv_pass<9, SY><<<grd, blk, 0, stream>>>(o[2], o[4], k20);
    conv_pass<9, 1 ><<<grd, blk, 0, stream>>>(o[4], o[5], k20);
    // G(3.0) -> o2
    conv_pass<13, SZ><<<grd, blk, 0, stream>>>(raw,  o[2], k30);
    conv_pass<13, SY><<<grd, blk, 0, stream>>>(o[2], o[4], k30);
    conv_pass<13, 1 ><<<grd, blk, 0, stream>>>(o[4], o[2], k30);
    // ch2 = G20 - G30 -> o2 (in-place elementwise safe)
    sub_kernel<<<grd, blk, 0, stream>>>(o[5], o[2], o[2]);
    // derivatives from G10 (o3): ch3->o0 (temp), ch4->o4, ch5->o5
    deriv_kernel<<<grd, blk, 0, stream>>>(o[3], o[0], o[4], o[5]);
    // move ch3 temp to o3, write ch0 = raw into o0
    finalize_kernel<<<grd, blk, 0, stream>>>(raw, o[0], o[3]);

    // per-channel mean / std, then normalize
    dim3 rgrd(1024, 6);
    reduce_kernel<<<rgrd, blk, 0, stream>>>(out, sums);
    normalize_kernel<<<(6 * V) / 256, blk, 0, stream>>>(out, sums);
}